// Round 1
// baseline (8363.322 us; speedup 1.0000x reference)
//
#include <hip/hip_runtime.h>
#include <hip/hip_bf16.h>

typedef unsigned short u16;
typedef __attribute__((ext_vector_type(8))) short bf16x8;
typedef __attribute__((ext_vector_type(4))) float f32x4;

static constexpr int V = 20000, H = 400, B = 16, S = 256, NSLOT = 30, T = 10, G = 3;
static constexpr int H3 = 3 * H;           // 1200
static constexpr int NB = NSLOT * B;       // 480
static constexpr int KP = 448;             // padded K for encoder Whh (448 = 8 slices * 56)

__device__ __forceinline__ float bf2f(u16 v) {
    union { unsigned u; float f; } x; x.u = ((unsigned)v) << 16; return x.f;
}
__device__ __forceinline__ u16 f2bf(float f) {
    union { float f; unsigned u; } x; x.f = f;
    unsigned r = x.u + 0x7fffu + ((x.u >> 16) & 1u);   // round-to-nearest-even
    return (u16)(r >> 16);
}

// ---------------------------------------------------------------------------
// Generic batched GEMM: C[m][n] = sum_k A[m][k] * Bt[n][k]  (+bias[n])
// A, Bt bf16 row-major; C f32. mode 0: plain (+bias). mode 1: C=exp(acc),
// atomicAdd per-row sums into rowsum (max-free softmax numerator pass).
// ---------------------------------------------------------------------------
__global__ __launch_bounds__(256) void gemm_bt(
    const u16* __restrict__ A, const u16* __restrict__ Bt,
    const float* __restrict__ bias, float* __restrict__ C,
    int M, int N, int K, int lda, int ldb, long long ldc,
    long long sA, long long sB, long long sC,
    int mode, float* __restrict__ rowsum)
{
    __shared__ u16 As[64][40];   // BK=32 +8 pad -> 80B row stride (2-way bank alias, free)
    __shared__ u16 Bs[64][40];
    const int bz = blockIdx.z;
    A  += (long long)bz * sA;
    Bt += (long long)bz * sB;
    C  += (long long)bz * sC;
    const int m0 = blockIdx.x * 64, n0 = blockIdx.y * 64;
    const int tid = threadIdx.x, wave = tid >> 6, lane = tid & 63;
    const int wm = (wave >> 1) * 32, wn = (wave & 1) * 32;
    const int srow = tid >> 2, scol = (tid & 3) * 8;
    const int fr = lane & 15, kq = lane >> 4;
    f32x4 acc[2][2];
#pragma unroll
    for (int i = 0; i < 2; ++i)
#pragma unroll
        for (int j = 0; j < 2; ++j) acc[i][j] = (f32x4){0.f, 0.f, 0.f, 0.f};

    for (int k0 = 0; k0 < K; k0 += 32) {
        {   // stage A tile (64x32), zero-fill OOB
            int gr = m0 + srow, gc = k0 + scol;
            bf16x8 v;
            if (gr < M && gc + 8 <= K) {
                v = *(const bf16x8*)(A + (long long)gr * lda + gc);
            } else {
                short tmp[8];
#pragma unroll
                for (int j = 0; j < 8; ++j)
                    tmp[j] = (gr < M && gc + j < K) ? (short)A[(long long)gr * lda + gc + j] : (short)0;
                v = *(bf16x8*)tmp;
            }
            *(bf16x8*)&As[srow][scol] = v;
        }
        {   // stage B tile
            int gr = n0 + srow, gc = k0 + scol;
            bf16x8 v;
            if (gr < N && gc + 8 <= K) {
                v = *(const bf16x8*)(Bt + (long long)gr * ldb + gc);
            } else {
                short tmp[8];
#pragma unroll
                for (int j = 0; j < 8; ++j)
                    tmp[j] = (gr < N && gc + j < K) ? (short)Bt[(long long)gr * ldb + gc + j] : (short)0;
                v = *(bf16x8*)tmp;
            }
            *(bf16x8*)&Bs[srow][scol] = v;
        }
        __syncthreads();
        bf16x8 af[2], bfr[2];
#pragma unroll
        for (int i = 0; i < 2; ++i) af[i]  = *(const bf16x8*)&As[wm + i * 16 + fr][kq * 8];
#pragma unroll
        for (int j = 0; j < 2; ++j) bfr[j] = *(const bf16x8*)&Bs[wn + j * 16 + fr][kq * 8];
#pragma unroll
        for (int i = 0; i < 2; ++i)
#pragma unroll
            for (int j = 0; j < 2; ++j)
                acc[i][j] = __builtin_amdgcn_mfma_f32_16x16x32_bf16(af[i], bfr[j], acc[i][j], 0, 0, 0);
        __syncthreads();
    }

    // epilogue: C/D layout col = lane&15, row = (lane>>4)*4 + r  [m89/m91 verified]
#pragma unroll
    for (int i = 0; i < 2; ++i)
#pragma unroll
        for (int j = 0; j < 2; ++j) {
            int col = n0 + wn + j * 16 + fr;
            float bv = (bias != nullptr && col < N) ? bias[col] : 0.f;
#pragma unroll
            for (int r = 0; r < 4; ++r) {
                int row = m0 + wm + i * 16 + kq * 4 + r;
                bool ok = (row < M) && (col < N);
                float v = acc[i][j][r] + bv;
                if (mode == 1) { v = ok ? __expf(v) : 0.f; acc[i][j][r] = v; }
                if (ok) C[(long long)row * ldc + col] = v;
            }
        }
    if (mode == 1) {
#pragma unroll
        for (int i = 0; i < 2; ++i)
#pragma unroll
            for (int r = 0; r < 4; ++r) {
                float s = acc[i][0][r] + acc[i][1][r];
                s += __shfl_xor(s, 1); s += __shfl_xor(s, 2);
                s += __shfl_xor(s, 4); s += __shfl_xor(s, 8);
                if (fr == 0) {
                    int row = m0 + wm + i * 16 + kq * 4 + r;
                    if (row < M) atomicAdd(&rowsum[row], s);
                }
            }
    }
}

// ---------------------------------------------------------------------------
// small utility kernels
// ---------------------------------------------------------------------------
__global__ void cvt_bf16_kernel(const float* __restrict__ src, u16* __restrict__ dst, int n) {
    for (int i = blockIdx.x * blockDim.x + threadIdx.x; i < n; i += gridDim.x * blockDim.x)
        dst[i] = f2bf(src[i]);
}

__global__ void cvt_pad_whh_kernel(const float* __restrict__ src, u16* __restrict__ dst) {
    int row = blockIdx.x;  // 0..1199
    for (int k = threadIdx.x; k < KP; k += blockDim.x)
        dst[(long long)row * KP + k] = (k < H) ? f2bf(src[(long long)row * H + k]) : (u16)0;
}

__global__ void embed_story_kernel(const int* __restrict__ story, const u16* __restrict__ embb,
                                   u16* __restrict__ xb) {
    int row = blockIdx.x;                 // row = s*16 + b
    int s = row >> 4, b = row & 15;
    int tok = story[b * S + s];
    const u16* e = embb + (long long)tok * H;
    u16* d = xb + (long long)row * H;
    for (int k = threadIdx.x; k < H; k += blockDim.x) d[k] = e[k];
}

__global__ void build_decin_kernel(const int* __restrict__ tgt, const int* __restrict__ dom,
                                   const int* __restrict__ sidx, const float* __restrict__ slt,
                                   const u16* __restrict__ embb, u16* __restrict__ decin) {
    int n = blockIdx.x, t = blockIdx.y;
    int b = n & 15, slot = n >> 4;
    u16* d = decin + ((long long)t * NB + n) * H;
    if (t == 0) {
        const float* s1 = slt + (long long)dom[slot] * H;
        const float* s2 = slt + (long long)sidx[slot] * H;
        for (int k = threadIdx.x; k < H; k += blockDim.x) d[k] = f2bf(s1[k] + s2[k]);
    } else {
        int tok = tgt[(b * NSLOT + slot) * T + (t - 1)];
        const u16* e = embb + (long long)tok * H;
        for (int k = threadIdx.x; k < H; k += blockDim.x) d[k] = e[k];
    }
}

// ---------------------------------------------------------------------------
// Encoder GRU recurrence: 32 persistent blocks = (dir, batch) chains.
// h in LDS; Whh pre-cast bf16 padded to K=448. gi precomputed.
// ---------------------------------------------------------------------------
__global__ __launch_bounds__(1024) void enc_rnn_kernel(
    const u16* __restrict__ WhhPf, const u16* __restrict__ WhhPb,
    const float* __restrict__ bhhf, const float* __restrict__ bhhb,
    const float* __restrict__ gif, const float* __restrict__ gib,
    const int* __restrict__ lens,
    float* __restrict__ ysf, float* __restrict__ ysb,
    float* __restrict__ hfo, float* __restrict__ hbo)
{
    const int blk = blockIdx.x, dir = blk >> 4, b = blk & 15;
    const u16* W = dir ? WhhPb : WhhPf;
    const float* bhh = dir ? bhhb : bhhf;
    const float* gi = dir ? gib : gif;
    float* ys = dir ? ysb : ysf;
    float* ho = dir ? hbo : hfo;
    const int len = lens[b];
    __shared__ float hsh[KP];
    __shared__ float ghsh[H3];
    const int tid = threadIdx.x, wave = tid >> 6, lane = tid & 63;
    const int rl = lane >> 3, ks = lane & 7, kbase = ks * 56;
    for (int i = tid; i < KP; i += 1024) hsh[i] = 0.f;
    __syncthreads();
    for (int t = 0; t < S; ++t) {
        const int s = dir ? (S - 1 - t) : t;
        const bool mask = s < len;          // block-uniform
        if (mask) {
            float hreg[56] __attribute__((aligned(16)));
#pragma unroll
            for (int q = 0; q < 14; ++q)
                *(f32x4*)&hreg[q * 4] = *(const f32x4*)&hsh[kbase + q * 4];
            const int rbase = wave * 75;    // 16 waves * 75 rows = 1200
            for (int p = 0; p < 10; ++p) {
                const int rr = p * 8 + rl;
                if (rr < 75) {
                    const int row = rbase + rr;
                    const u16* wr = W + (long long)row * KP + kbase;
                    float sum = 0.f;
#pragma unroll
                    for (int q = 0; q < 7; ++q) {
                        bf16x8 wv = *(const bf16x8*)(wr + q * 8);
#pragma unroll
                        for (int j = 0; j < 8; ++j)
                            sum = fmaf(bf2f((u16)wv[j]), hreg[q * 8 + j], sum);
                    }
                    sum += __shfl_xor(sum, 1);
                    sum += __shfl_xor(sum, 2);
                    sum += __shfl_xor(sum, 4);
                    if (ks == 0) ghsh[row] = sum + bhh[row];
                }
            }
        }
        __syncthreads();
        if (tid < H) {
            float y = 0.f;
            if (mask) {
                const float* gr = gi + ((long long)(s * B + b)) * H3;
                float r  = 1.f / (1.f + __expf(-(gr[tid]         + ghsh[tid])));
                float z  = 1.f / (1.f + __expf(-(gr[H + tid]     + ghsh[H + tid])));
                float nn = tanhf(gr[2 * H + tid] + r * ghsh[2 * H + tid]);
                float hnew = (1.f - z) * nn + z * hsh[tid];
                hsh[tid] = hnew;
                y = hnew;
            }
            ys[((long long)b * S + s) * H + tid] = y;
        }
        __syncthreads();
    }
    if (tid < H) ho[b * H + tid] = hsh[tid];
}

// E = ys_f + ys_b (bf16, [b][s][k]) and ET (bf16, [b][k][s])
__global__ void packE_kernel(const float* __restrict__ ysf, const float* __restrict__ ysb,
                             u16* __restrict__ E, u16* __restrict__ ET) {
    __shared__ u16 tile[32][400];
    const int b = blockIdx.x, s0 = blockIdx.y * 32;
    for (int si = 0; si < 32; ++si) {
        const long long base = ((long long)b * S + s0 + si) * H;
        for (int k = threadIdx.x; k < H; k += blockDim.x) {
            u16 v = f2bf(ysf[base + k] + ysb[base + k]);
            E[base + k] = v;
            tile[si][k] = v;
        }
    }
    __syncthreads();
    for (int idx = threadIdx.x; idx < 32 * H; idx += blockDim.x) {
        int k = idx >> 5, si = idx & 31;
        ET[((long long)b * H + k) * S + s0 + si] = tile[si][k];
    }
}

__global__ void h0_kernel(const float* __restrict__ hf, const float* __restrict__ hb,
                          float* __restrict__ hf32, u16* __restrict__ hnk, u16* __restrict__ hbsk) {
    int n = blockIdx.x, b = n & 15, slot = n >> 4;
    for (int k = threadIdx.x; k < H; k += blockDim.x) {
        float v = hf[b * H + k] + hb[b * H + k];
        hf32[(long long)n * H + k] = v;
        u16 bv = f2bf(v);
        hnk[(long long)n * H + k] = bv;
        hbsk[((long long)(b * NSLOT + slot)) * H + k] = bv;
    }
}

__global__ void dec_gru_kernel(const float* __restrict__ dgi, const float* __restrict__ dgh,
                               float* __restrict__ hf32, u16* __restrict__ hnk,
                               u16* __restrict__ hbsk, int t) {
    int n = blockIdx.x, b = n & 15, slot = n >> 4;
    const float* gi = dgi + ((long long)t * NB + n) * H3;
    const float* gh = dgh + (long long)n * H3;
    for (int k = threadIdx.x; k < H; k += blockDim.x) {
        float r  = 1.f / (1.f + __expf(-(gi[k]         + gh[k])));
        float z  = 1.f / (1.f + __expf(-(gi[H + k]     + gh[H + k])));
        float nn = tanhf(gi[2 * H + k] + r * gh[2 * H + k]);
        float h  = hf32[(long long)n * H + k];
        float hn = (1.f - z) * nn + z * h;
        hf32[(long long)n * H + k] = hn;
        u16 bv = f2bf(hn);
        hnk[(long long)n * H + k] = bv;
        hbsk[((long long)(b * NSLOT + slot)) * H + k] = bv;
    }
}

__global__ __launch_bounds__(256) void attn_softmax_kernel(
    const float* __restrict__ scores, const int* __restrict__ lens,
    float* __restrict__ probf, u16* __restrict__ probb) {
    const int n = blockIdx.x, b = n & 15, slot = n >> 4;
    const int s = threadIdx.x, lane = s & 63, wave = s >> 6;
    const int len = lens[b];
    __shared__ float red[4];
    __shared__ float bc;
    const long long srow = ((long long)(b * NSLOT + slot)) * S;
    float sc = (s < len) ? scores[srow + s] : -3.0e38f;
    float m = sc;
    m = fmaxf(m, __shfl_xor(m, 1));  m = fmaxf(m, __shfl_xor(m, 2));
    m = fmaxf(m, __shfl_xor(m, 4));  m = fmaxf(m, __shfl_xor(m, 8));
    m = fmaxf(m, __shfl_xor(m, 16)); m = fmaxf(m, __shfl_xor(m, 32));
    if (lane == 0) red[wave] = m;
    __syncthreads();
    if (s == 0) bc = fmaxf(fmaxf(red[0], red[1]), fmaxf(red[2], red[3]));
    __syncthreads();
    const float mx = bc;
    float e = (s < len) ? __expf(sc - mx) : 0.f;
    float sum = e;
    sum += __shfl_xor(sum, 1);  sum += __shfl_xor(sum, 2);
    sum += __shfl_xor(sum, 4);  sum += __shfl_xor(sum, 8);
    sum += __shfl_xor(sum, 16); sum += __shfl_xor(sum, 32);
    __syncthreads();
    if (lane == 0) red[wave] = sum;
    __syncthreads();
    if (s == 0) bc = red[0] + red[1] + red[2] + red[3];
    __syncthreads();
    const float p = e / bc;
    probf[(long long)n * S + s] = p;
    probb[srow + s] = f2bf(p);
}

__global__ __launch_bounds__(256) void sw_kernel(
    const float* __restrict__ hf32, const float* __restrict__ ctx,
    const u16* __restrict__ decin, const float* __restrict__ Wr,
    const float* __restrict__ br, float* __restrict__ sw, int t) {
    const int n = blockIdx.x, b = n & 15, slot = n >> 4;
    const int tid = threadIdx.x, lane = tid & 63, wave = tid >> 6;
    __shared__ float red[4];
    float p = 0.f;
    const float* hrow = hf32 + (long long)n * H;
    const float* crow = ctx + ((long long)(b * NSLOT + slot)) * H;
    const u16*  xrow = decin + ((long long)t * NB + n) * H;
    for (int k = tid; k < H; k += 256)
        p += hrow[k] * Wr[k] + crow[k] * Wr[H + k] + bf2f(xrow[k]) * Wr[2 * H + k];
    p += __shfl_xor(p, 1);  p += __shfl_xor(p, 2);
    p += __shfl_xor(p, 4);  p += __shfl_xor(p, 8);
    p += __shfl_xor(p, 16); p += __shfl_xor(p, 32);
    if (lane == 0) red[wave] = p;
    __syncthreads();
    if (tid == 0) {
        float v = red[0] + red[1] + red[2] + red[3] + br[0];
        sw[n] = 1.f / (1.f + __expf(-v));
    }
}

__global__ void scale_kernel(float* __restrict__ out, const float* __restrict__ sw,
                             const float* __restrict__ rowsum, int t) {
    const int n = blockIdx.x;
    const float f = sw[n] / rowsum[n];
    float* row = out + ((long long)n * T + t) * V;
    const int col = blockIdx.y * 256 + threadIdx.x;
    if (col < V) row[col] *= f;
}

__global__ void scatter_kernel(float* __restrict__ out, const int* __restrict__ story,
                               const int* __restrict__ lens, const float* __restrict__ sw,
                               const float* __restrict__ probf, int t) {
    const int n = blockIdx.x, b = n & 15, s = threadIdx.x;
    if (s < lens[b]) {
        int tok = story[b * S + s];
        atomicAdd(out + ((long long)n * T + t) * V + tok,
                  (1.f - sw[n]) * probf[(long long)n * S + s]);
    }
}

__global__ __launch_bounds__(64) void gate_kernel(const float* __restrict__ ctx,
                                                  const float* __restrict__ Wg,
                                                  const float* __restrict__ bg,
                                                  float* __restrict__ gout) {
    const int n = blockIdx.x, b = n & 15, slot = n >> 4, lane = threadIdx.x;
    const float* crow = ctx + ((long long)(b * NSLOT + slot)) * H;
    for (int g = 0; g < G; ++g) {
        float p = 0.f;
        for (int k = lane; k < H; k += 64) p += crow[k] * Wg[g * H + k];
        p += __shfl_xor(p, 1);  p += __shfl_xor(p, 2);
        p += __shfl_xor(p, 4);  p += __shfl_xor(p, 8);
        p += __shfl_xor(p, 16); p += __shfl_xor(p, 32);
        if (lane == 0) gout[(long long)n * G + g] = p + bg[g];
    }
}

// ---------------------------------------------------------------------------
extern "C" void kernel_launch(void* const* d_in, const int* in_sizes, int n_in,
                              void* d_out, int out_size, void* d_ws, size_t ws_size,
                              hipStream_t stream) {
    const int*   story = (const int*)d_in[0];
    const int*   lens  = (const int*)d_in[1];
    const int*   tgt   = (const int*)d_in[2];
    const int*   dom   = (const int*)d_in[3];
    const int*   sidx  = (const int*)d_in[4];
    const float* emb   = (const float*)d_in[5];
    const float* wihf  = (const float*)d_in[6];
    const float* whhf  = (const float*)d_in[7];
    const float* bihf  = (const float*)d_in[8];
    const float* bhhf  = (const float*)d_in[9];
    const float* wihb  = (const float*)d_in[10];
    const float* whhb  = (const float*)d_in[11];
    const float* bihb  = (const float*)d_in[12];
    const float* bhhb  = (const float*)d_in[13];
    const float* dwih  = (const float*)d_in[14];
    const float* dwhh  = (const float*)d_in[15];
    const float* dbih  = (const float*)d_in[16];
    const float* dbhh  = (const float*)d_in[17];
    const float* Wr    = (const float*)d_in[18];
    const float* br    = (const float*)d_in[19];
    const float* Wg    = (const float*)d_in[20];
    const float* bg    = (const float*)d_in[21];
    const float* slt   = (const float*)d_in[22];
    float* out = (float*)d_out;

    char* wsb = (char*)d_ws;
    size_t off = 0;
    auto alloc = [&](size_t bytes) -> char* {
        char* p = wsb + off;
        off += (bytes + 255) & ~(size_t)255;
        return p;
    };
    u16*   embb   = (u16*)alloc((size_t)V * H * 2);
    u16*   wihfb  = (u16*)alloc((size_t)H3 * H * 2);
    u16*   wihbb  = (u16*)alloc((size_t)H3 * H * 2);
    u16*   dwihb  = (u16*)alloc((size_t)H3 * H * 2);
    u16*   dwhhb  = (u16*)alloc((size_t)H3 * H * 2);
    u16*   whhfp  = (u16*)alloc((size_t)H3 * KP * 2);
    u16*   whhbp  = (u16*)alloc((size_t)H3 * KP * 2);
    u16*   xb     = (u16*)alloc((size_t)S * B * H * 2);
    u16*   decinb = (u16*)alloc((size_t)T * NB * H * 2);
    float* gif    = (float*)alloc((size_t)S * B * H3 * 4);
    float* gib    = (float*)alloc((size_t)S * B * H3 * 4);
    float* dgi    = (float*)alloc((size_t)T * NB * H3 * 4);
    float* ysf    = (float*)alloc((size_t)B * S * H * 4);
    float* ysb    = (float*)alloc((size_t)B * S * H * 4);
    float* hfv    = (float*)alloc((size_t)B * H * 4);
    float* hbv    = (float*)alloc((size_t)B * H * 4);
    u16*   Eb     = (u16*)alloc((size_t)B * S * H * 2);
    u16*   ETb    = (u16*)alloc((size_t)B * H * S * 2);
    float* hf32   = (float*)alloc((size_t)NB * H * 4);
    u16*   hnk    = (u16*)alloc((size_t)NB * H * 2);
    u16*   hbsk   = (u16*)alloc((size_t)NB * H * 2);
    float* dgh    = (float*)alloc((size_t)NB * H3 * 4);
    float* scores = (float*)alloc((size_t)NB * S * 4);
    float* probf  = (float*)alloc((size_t)NB * S * 4);
    u16*   probb  = (u16*)alloc((size_t)NB * S * 2);
    float* ctx    = (float*)alloc((size_t)NB * H * 4);
    float* swv    = (float*)alloc((size_t)NB * 4);
    float* rowsum = (float*)alloc((size_t)NB * 4);
    (void)ws_size; (void)in_sizes; (void)n_in; (void)out_size;

    auto launch_gemm = [&](const u16* A, const u16* Bt, const float* bias, float* C,
                           int M, int N, int K, int lda, int ldb, long long ldc,
                           long long sA, long long sB, long long sC, int nb,
                           int mode, float* rs) {
        dim3 g((M + 63) / 64, (N + 63) / 64, nb);
        gemm_bt<<<g, 256, 0, stream>>>(A, Bt, bias, C, M, N, K, lda, ldb, ldc,
                                       sA, sB, sC, mode, rs);
    };

    // ---- setup: casts, embeddings, input-side GEMMs -----------------------
    cvt_bf16_kernel<<<2048, 256, 0, stream>>>(emb, embb, V * H);
    cvt_bf16_kernel<<<512, 256, 0, stream>>>(wihf, wihfb, H3 * H);
    cvt_bf16_kernel<<<512, 256, 0, stream>>>(wihb, wihbb, H3 * H);
    cvt_bf16_kernel<<<512, 256, 0, stream>>>(dwih, dwihb, H3 * H);
    cvt_bf16_kernel<<<512, 256, 0, stream>>>(dwhh, dwhhb, H3 * H);
    cvt_pad_whh_kernel<<<H3, 256, 0, stream>>>(whhf, whhfp);
    cvt_pad_whh_kernel<<<H3, 256, 0, stream>>>(whhb, whhbp);
    embed_story_kernel<<<S * B, 256, 0, stream>>>(story, embb, xb);
    { dim3 g(NB, T); build_decin_kernel<<<g, 256, 0, stream>>>(tgt, dom, sidx, slt, embb, decinb); }

    launch_gemm(xb, wihfb, bihf, gif, S * B, H3, H, H, H, H3, 0, 0, 0, 1, 0, nullptr);
    launch_gemm(xb, wihbb, bihb, gib, S * B, H3, H, H, H, H3, 0, 0, 0, 1, 0, nullptr);
    launch_gemm(decinb, dwihb, dbih, dgi, T * NB, H3, H, H, H, H3, 0, 0, 0, 1, 0, nullptr);

    // ---- encoder recurrence ----------------------------------------------
    enc_rnn_kernel<<<32, 1024, 0, stream>>>(whhfp, whhbp, bhhf, bhhb, gif, gib, lens,
                                            ysf, ysb, hfv, hbv);
    { dim3 g(B, S / 32); packE_kernel<<<g, 256, 0, stream>>>(ysf, ysb, Eb, ETb); }
    h0_kernel<<<NB, 256, 0, stream>>>(hfv, hbv, hf32, hnk, hbsk);

    // ---- decoder ----------------------------------------------------------
    for (int t = 0; t < T; ++t) {
        launch_gemm(hnk, dwhhb, dbhh, dgh, NB, H3, H, H, H, H3, 0, 0, 0, 1, 0, nullptr);
        dec_gru_kernel<<<NB, 256, 0, stream>>>(dgi, dgh, hf32, hnk, hbsk, t);
        // attention scores: per-batch GEMM (A = h[b][slot][:], Bt = E[b][s][:])
        launch_gemm(hbsk, Eb, nullptr, scores, NSLOT, S, H, H, H, S,
                    (long long)NSLOT * H, (long long)S * H, (long long)NSLOT * S, B, 0, nullptr);
        attn_softmax_kernel<<<NB, 256, 0, stream>>>(scores, lens, probf, probb);
        // context: per-batch GEMM (A = prob[b][slot][:], Bt = ET[b][k][:])
        launch_gemm(probb, ETb, nullptr, ctx, NSLOT, H, S, S, S, H,
                    (long long)NSLOT * S, (long long)H * S, (long long)NSLOT * H, B, 0, nullptr);
        if (t == 0)
            gate_kernel<<<NB, 64, 0, stream>>>(ctx, Wg, bg, out + (size_t)NB * T * V);
        sw_kernel<<<NB, 256, 0, stream>>>(hf32, ctx, decinb, Wr, br, swv, t);
        hipMemsetAsync(rowsum, 0, NB * sizeof(float), stream);
        // vocab projection with fused exp + row sums, written straight into d_out
        launch_gemm(hnk, embb, nullptr, out + (size_t)t * V, NB, V, H, H, H,
                    (long long)T * V, 0, 0, 0, 1, 1, rowsum);
        { dim3 g(NB, (V + 255) / 256); scale_kernel<<<g, 256, 0, stream>>>(out, swv, rowsum, t); }
        scatter_kernel<<<NB, 256, 0, stream>>>(out, story, lens, swv, probf, t);
    }
}

// Round 2
// 3879.085 us; speedup vs baseline: 2.1560x; 2.1560x over previous
//
#include <hip/hip_runtime.h>
#include <hip/hip_bf16.h>

typedef unsigned short u16;
typedef __attribute__((ext_vector_type(8))) short bf16x8;
typedef __attribute__((ext_vector_type(4))) float f32x4;

static constexpr int V = 20000, H = 400, B = 16, S = 256, NSLOT = 30, T = 10, G = 3;
static constexpr int H3 = 3 * H;           // 1200
static constexpr int NB = NSLOT * B;       // 480
// encoder partition
static constexpr int ENBLK = 20;           // blocks per direction
static constexpr int ESL   = 20;           // h components per block (400/20)
static constexpr int EROWS = 64;           // padded weight rows per block (3*20 -> 64)
static constexpr int EKP   = 416;          // padded K (400 -> 416)
static constexpr int HROW  = 832;          // hbuf row stride (hi 416 + lo 416)

__device__ __forceinline__ float bf2f(u16 v) {
    union { unsigned u; float f; } x; x.u = ((unsigned)v) << 16; return x.f;
}
__device__ __forceinline__ u16 f2bf(float f) {
    union { float f; unsigned u; } x; x.f = f;
    unsigned r = x.u + 0x7fffu + ((x.u >> 16) & 1u);   // round-to-nearest-even
    return (u16)(r >> 16);
}

// ---------------------------------------------------------------------------
// Generic batched GEMM: C[m][n] = sum_k A[m][k] * Bt[n][k]  (+bias[n])
// mode 0: plain (+bias). mode 1: C=exp(acc), atomicAdd row sums (softmax num).
// ---------------------------------------------------------------------------
__global__ __launch_bounds__(256) void gemm_bt(
    const u16* __restrict__ A, const u16* __restrict__ Bt,
    const float* __restrict__ bias, float* __restrict__ C,
    int M, int N, int K, int lda, int ldb, long long ldc,
    long long sA, long long sB, long long sC,
    int mode, float* __restrict__ rowsum)
{
    __shared__ u16 As[64][40];
    __shared__ u16 Bs[64][40];
    const int bz = blockIdx.z;
    A  += (long long)bz * sA;
    Bt += (long long)bz * sB;
    C  += (long long)bz * sC;
    const int m0 = blockIdx.x * 64, n0 = blockIdx.y * 64;
    const int tid = threadIdx.x, wave = tid >> 6, lane = tid & 63;
    const int wm = (wave >> 1) * 32, wn = (wave & 1) * 32;
    const int srow = tid >> 2, scol = (tid & 3) * 8;
    const int fr = lane & 15, kq = lane >> 4;
    f32x4 acc[2][2];
#pragma unroll
    for (int i = 0; i < 2; ++i)
#pragma unroll
        for (int j = 0; j < 2; ++j) acc[i][j] = (f32x4){0.f, 0.f, 0.f, 0.f};

    for (int k0 = 0; k0 < K; k0 += 32) {
        {
            int gr = m0 + srow, gc = k0 + scol;
            bf16x8 v;
            if (gr < M && gc + 8 <= K) {
                v = *(const bf16x8*)(A + (long long)gr * lda + gc);
            } else {
                short tmp[8];
#pragma unroll
                for (int j = 0; j < 8; ++j)
                    tmp[j] = (gr < M && gc + j < K) ? (short)A[(long long)gr * lda + gc + j] : (short)0;
                v = *(bf16x8*)tmp;
            }
            *(bf16x8*)&As[srow][scol] = v;
        }
        {
            int gr = n0 + srow, gc = k0 + scol;
            bf16x8 v;
            if (gr < N && gc + 8 <= K) {
                v = *(const bf16x8*)(Bt + (long long)gr * ldb + gc);
            } else {
                short tmp[8];
#pragma unroll
                for (int j = 0; j < 8; ++j)
                    tmp[j] = (gr < N && gc + j < K) ? (short)Bt[(long long)gr * ldb + gc + j] : (short)0;
                v = *(bf16x8*)tmp;
            }
            *(bf16x8*)&Bs[srow][scol] = v;
        }
        __syncthreads();
        bf16x8 af[2], bfr[2];
#pragma unroll
        for (int i = 0; i < 2; ++i) af[i]  = *(const bf16x8*)&As[wm + i * 16 + fr][kq * 8];
#pragma unroll
        for (int j = 0; j < 2; ++j) bfr[j] = *(const bf16x8*)&Bs[wn + j * 16 + fr][kq * 8];
#pragma unroll
        for (int i = 0; i < 2; ++i)
#pragma unroll
            for (int j = 0; j < 2; ++j)
                acc[i][j] = __builtin_amdgcn_mfma_f32_16x16x32_bf16(af[i], bfr[j], acc[i][j], 0, 0, 0);
        __syncthreads();
    }

#pragma unroll
    for (int i = 0; i < 2; ++i)
#pragma unroll
        for (int j = 0; j < 2; ++j) {
            int col = n0 + wn + j * 16 + fr;
            float bv = (bias != nullptr && col < N) ? bias[col] : 0.f;
#pragma unroll
            for (int r = 0; r < 4; ++r) {
                int row = m0 + wm + i * 16 + kq * 4 + r;
                bool ok = (row < M) && (col < N);
                float v = acc[i][j][r] + bv;
                if (mode == 1) { v = ok ? __expf(v) : 0.f; acc[i][j][r] = v; }
                if (ok) C[(long long)row * ldc + col] = v;
            }
        }
    if (mode == 1) {
#pragma unroll
        for (int i = 0; i < 2; ++i)
#pragma unroll
            for (int r = 0; r < 4; ++r) {
                float s = acc[i][0][r] + acc[i][1][r];
                s += __shfl_xor(s, 1); s += __shfl_xor(s, 2);
                s += __shfl_xor(s, 4); s += __shfl_xor(s, 8);
                if (fr == 0) {
                    int row = m0 + wm + i * 16 + kq * 4 + r;
                    if (row < M) atomicAdd(&rowsum[row], s);
                }
            }
    }
}

// ---------------------------------------------------------------------------
// small utility kernels
// ---------------------------------------------------------------------------
__global__ void cvt_bf16_kernel(const float* __restrict__ src, u16* __restrict__ dst, int n) {
    for (int i = blockIdx.x * blockDim.x + threadIdx.x; i < n; i += gridDim.x * blockDim.x)
        dst[i] = f2bf(src[i]);
}

// weight prep for the distributed encoder: dst[dir][j][rloc][k], rloc = g*20+c
// covers rows {g*H + j*20 + c}; zero-padded rows 60..63 and k 400..415.
__global__ void prep_wenc_kernel(const float* __restrict__ whhf, const float* __restrict__ whhb,
                                 u16* __restrict__ dst) {
    int idx = blockIdx.x * 256 + threadIdx.x;
    const int total = 2 * ENBLK * EROWS * EKP;
    if (idx >= total) return;
    int k = idx % EKP; int r = idx / EKP;
    int rloc = r % EROWS; r /= EROWS;
    int j = r % ENBLK; int dir = r / ENBLK;
    u16 v = 0;
    if (k < H && rloc < 3 * ESL) {
        int g = rloc / ESL, c = rloc % ESL;
        const float* W = dir ? whhb : whhf;
        v = f2bf(W[(long long)(g * H + j * ESL + c) * H + k]);
    }
    dst[idx] = v;
}

__global__ void embed_story_kernel(const int* __restrict__ story, const u16* __restrict__ embb,
                                   u16* __restrict__ xb) {
    int row = blockIdx.x;                 // row = s*16 + b
    int s = row >> 4, b = row & 15;
    int tok = story[b * S + s];
    const u16* e = embb + (long long)tok * H;
    u16* d = xb + (long long)row * H;
    for (int k = threadIdx.x; k < H; k += blockDim.x) d[k] = e[k];
}

__global__ void build_decin_kernel(const int* __restrict__ tgt, const int* __restrict__ dom,
                                   const int* __restrict__ sidx, const float* __restrict__ slt,
                                   const u16* __restrict__ embb, u16* __restrict__ decin) {
    int n = blockIdx.x, t = blockIdx.y;
    int b = n & 15, slot = n >> 4;
    u16* d = decin + ((long long)t * NB + n) * H;
    if (t == 0) {
        const float* s1 = slt + (long long)dom[slot] * H;
        const float* s2 = slt + (long long)sidx[slot] * H;
        for (int k = threadIdx.x; k < H; k += blockDim.x) d[k] = f2bf(s1[k] + s2[k]);
    } else {
        int tok = tgt[(b * NSLOT + slot) * T + (t - 1)];
        const u16* e = embb + (long long)tok * H;
        for (int k = threadIdx.x; k < H; k += blockDim.x) d[k] = e[k];
    }
}

// ---------------------------------------------------------------------------
// Distributed encoder recurrence: 40 blocks = 2 dirs x 20 slices.
// Each block holds 64x416 bf16 Whh rows in LDS, computes gh for its rows for
// all 16 batches via MFMA, updates its 20-component h slice, publishes the
// slice (bf16 hi+lo) to a ping-pong global buffer, and syncs via agent-scope
// flags (release/acquire handles cross-XCD L2 non-coherence).
// ---------------------------------------------------------------------------
__global__ __launch_bounds__(256) void enc_rnn2_kernel(
    const u16* __restrict__ wencp,
    const float* __restrict__ bhhf, const float* __restrict__ bhhb,
    const float* __restrict__ gif, const float* __restrict__ gib,
    const int* __restrict__ lens,
    u16* __restrict__ hbuf, int* __restrict__ flags,
    float* __restrict__ ysf, float* __restrict__ ysb,
    float* __restrict__ hfo, float* __restrict__ hbo)
{
    const int bid = blockIdx.x;
    const int dir = bid / ENBLK, j = bid % ENBLK;
    const float* bhh = dir ? bhhb : bhhf;
    const float* gi  = dir ? gib  : gif;
    float* ys = dir ? ysb : ysf;
    float* ho = dir ? hbo : hfo;

    __shared__ u16 wlds[EROWS * EKP];      // 53248 B
    __shared__ float ghs[EROWS * 17];      // 4352 B (stride 17 -> conflict-free D write)

    const int tid = threadIdx.x, wave = tid >> 6, lane = tid & 63;
    const int fr = lane & 15, kq = lane >> 4;

    // stage weights (64*416 = 26624 elems = 3328 x 8; 256 thr * 13 iters exact)
    const u16* wsrc = wencp + (long long)(dir * ENBLK + j) * EROWS * EKP;
    for (int i = tid * 8; i < EROWS * EKP; i += 256 * 8)
        *(bf16x8*)&wlds[i] = *(const bf16x8*)&wsrc[i];
    for (int i = tid; i < EROWS * 17; i += 256) ghs[i] = 0.f;

    // (b, k_local) pair ownership: pair = b*20 + kl; thread owns tid and 256+tid
    const int p0 = tid, p1 = 256 + tid;
    const bool has1 = (tid < 64);
    const int b0 = p0 / ESL, kl0 = p0 % ESL;
    const int b1 = has1 ? p1 / ESL : 0, kl1 = has1 ? p1 % ESL : 0;
    const int k0 = j * ESL;
    const int len0 = lens[b0];
    const int len1 = has1 ? lens[b1] : 0;
    const float bhr0 = bhh[k0 + kl0], bhz0 = bhh[H + k0 + kl0], bhn0 = bhh[2 * H + k0 + kl0];
    const float bhr1 = has1 ? bhh[k0 + kl1] : 0.f;
    const float bhz1 = has1 ? bhh[H + k0 + kl1] : 0.f;
    const float bhn1 = has1 ? bhh[2 * H + k0 + kl1] : 0.f;
    float h0r = 0.f, h1r = 0.f;

    const int fbase = dir * ENBLK;
    u16* hb_d = hbuf + (long long)dir * 2 * B * HROW;
    __syncthreads();

    for (int t = 0; t < S; ++t) {
        const int s = dir ? (S - 1 - t) : t;
        // prefetch gi triples (HBM latency hides under poll+GEMM)
        const float* gbase = gi + (long long)s * B * H3;
        float gr0 = gbase[b0 * H3 + k0 + kl0];
        float gz0 = gbase[b0 * H3 + H + k0 + kl0];
        float gn0 = gbase[b0 * H3 + 2 * H + k0 + kl0];
        float gr1 = 0.f, gz1 = 0.f, gn1 = 0.f;
        if (has1) {
            gr1 = gbase[b1 * H3 + k0 + kl1];
            gz1 = gbase[b1 * H3 + H + k0 + kl1];
            gn1 = gbase[b1 * H3 + 2 * H + k0 + kl1];
        }

        f32x4 acc = (f32x4){0.f, 0.f, 0.f, 0.f};
        if (t > 0) {
            // wait for all 20 peer slices of h_t (acquire -> stale-L2 invalidate)
            for (;;) {
                int v = 0x7fffffff;
                if (lane < ENBLK)
                    v = __hip_atomic_load(&flags[fbase + lane], __ATOMIC_ACQUIRE,
                                          __HIP_MEMORY_SCOPE_AGENT);
                if (__all(v >= t)) break;
            }
            const u16* hrow = hb_d + (long long)(t & 1) * B * HROW + (long long)fr * HROW + kq * 8;
            const u16* arow = &wlds[(wave * 16 + fr) * EKP + kq * 8];
#pragma unroll
            for (int kk = 0; kk < 13; ++kk) {
                bf16x8 av = *(const bf16x8*)(arow + kk * 32);
                bf16x8 bh = *(const bf16x8*)(hrow + kk * 32);
                acc = __builtin_amdgcn_mfma_f32_16x16x32_bf16(av, bh, acc, 0, 0, 0);
            }
#pragma unroll
            for (int kk = 0; kk < 13; ++kk) {
                bf16x8 av = *(const bf16x8*)(arow + kk * 32);
                bf16x8 bl = *(const bf16x8*)(hrow + EKP + kk * 32);
                acc = __builtin_amdgcn_mfma_f32_16x16x32_bf16(av, bl, acc, 0, 0, 0);
            }
        }
        // D frag -> ghs: row = wave*16 + kq*4 + r, col = fr (batch)
#pragma unroll
        for (int r = 0; r < 4; ++r) ghs[(wave * 16 + kq * 4 + r) * 17 + fr] = acc[r];
        __syncthreads();

        // GRU cell for owned (b, kl) pairs
        u16* hpub = hb_d + (long long)((t + 1) & 1) * B * HROW;
        {
            float ghr = ghs[kl0 * 17 + b0];
            float ghz = ghs[(ESL + kl0) * 17 + b0];
            float ghn = ghs[(2 * ESL + kl0) * 17 + b0];
            float rg = 1.f / (1.f + __expf(-(gr0 + ghr + bhr0)));
            float zg = 1.f / (1.f + __expf(-(gz0 + ghz + bhz0)));
            float ng = tanhf(gn0 + rg * (ghn + bhn0));
            float hn = (1.f - zg) * ng + zg * h0r;
            bool msk = s < len0;
            float y = msk ? hn : 0.f;
            if (msk) h0r = hn;
            ys[((long long)(b0 * S + s)) * H + k0 + kl0] = y;
            u16 hi = f2bf(h0r);
            hpub[b0 * HROW + k0 + kl0] = hi;
            hpub[b0 * HROW + EKP + k0 + kl0] = f2bf(h0r - bf2f(hi));
        }
        if (has1) {
            float ghr = ghs[kl1 * 17 + b1];
            float ghz = ghs[(ESL + kl1) * 17 + b1];
            float ghn = ghs[(2 * ESL + kl1) * 17 + b1];
            float rg = 1.f / (1.f + __expf(-(gr1 + ghr + bhr1)));
            float zg = 1.f / (1.f + __expf(-(gz1 + ghz + bhz1)));
            float ng = tanhf(gn1 + rg * (ghn + bhn1));
            float hn = (1.f - zg) * ng + zg * h1r;
            bool msk = s < len1;
            float y = msk ? hn : 0.f;
            if (msk) h1r = hn;
            ys[((long long)(b1 * S + s)) * H + k0 + kl1] = y;
            u16 hi = f2bf(h1r);
            hpub[b1 * HROW + k0 + kl1] = hi;
            hpub[b1 * HROW + EKP + k0 + kl1] = f2bf(h1r - bf2f(hi));
        }
        // barrier drains every wave's stores (vmcnt0) before the release flag
        __syncthreads();
        if (tid == 0)
            __hip_atomic_store(&flags[fbase + j], t + 1, __ATOMIC_RELEASE,
                               __HIP_MEMORY_SCOPE_AGENT);
    }
    ho[b0 * H + k0 + kl0] = h0r;
    if (has1) ho[b1 * H + k0 + kl1] = h1r;
}

// E = ys_f + ys_b (bf16, [b][s][k]) and ET (bf16, [b][k][s])
__global__ void packE_kernel(const float* __restrict__ ysf, const float* __restrict__ ysb,
                             u16* __restrict__ E, u16* __restrict__ ET) {
    __shared__ u16 tile[32][400];
    const int b = blockIdx.x, s0 = blockIdx.y * 32;
    for (int si = 0; si < 32; ++si) {
        const long long base = ((long long)b * S + s0 + si) * H;
        for (int k = threadIdx.x; k < H; k += blockDim.x) {
            u16 v = f2bf(ysf[base + k] + ysb[base + k]);
            E[base + k] = v;
            tile[si][k] = v;
        }
    }
    __syncthreads();
    for (int idx = threadIdx.x; idx < 32 * H; idx += blockDim.x) {
        int k = idx >> 5, si = idx & 31;
        ET[((long long)b * H + k) * S + s0 + si] = tile[si][k];
    }
}

__global__ void h0_kernel(const float* __restrict__ hf, const float* __restrict__ hb,
                          float* __restrict__ hf32, u16* __restrict__ hnk, u16* __restrict__ hbsk) {
    int n = blockIdx.x, b = n & 15, slot = n >> 4;
    for (int k = threadIdx.x; k < H; k += blockDim.x) {
        float v = hf[b * H + k] + hb[b * H + k];
        hf32[(long long)n * H + k] = v;
        u16 bv = f2bf(v);
        hnk[(long long)n * H + k] = bv;
        hbsk[((long long)(b * NSLOT + slot)) * H + k] = bv;
    }
}

__global__ void dec_gru_kernel(const float* __restrict__ dgi, const float* __restrict__ dgh,
                               float* __restrict__ hf32, u16* __restrict__ hnk,
                               u16* __restrict__ hbsk, int t) {
    int n = blockIdx.x, b = n & 15, slot = n >> 4;
    const float* gi = dgi + ((long long)t * NB + n) * H3;
    const float* gh = dgh + (long long)n * H3;
    for (int k = threadIdx.x; k < H; k += blockDim.x) {
        float r  = 1.f / (1.f + __expf(-(gi[k]         + gh[k])));
        float z  = 1.f / (1.f + __expf(-(gi[H + k]     + gh[H + k])));
        float nn = tanhf(gi[2 * H + k] + r * gh[2 * H + k]);
        float h  = hf32[(long long)n * H + k];
        float hn = (1.f - z) * nn + z * h;
        hf32[(long long)n * H + k] = hn;
        u16 bv = f2bf(hn);
        hnk[(long long)n * H + k] = bv;
        hbsk[((long long)(b * NSLOT + slot)) * H + k] = bv;
    }
}

__global__ __launch_bounds__(256) void attn_softmax_kernel(
    const float* __restrict__ scores, const int* __restrict__ lens,
    float* __restrict__ probf, u16* __restrict__ probb) {
    const int n = blockIdx.x, b = n & 15, slot = n >> 4;
    const int s = threadIdx.x, lane = s & 63, wave = s >> 6;
    const int len = lens[b];
    __shared__ float red[4];
    __shared__ float bc;
    const long long srow = ((long long)(b * NSLOT + slot)) * S;
    float sc = (s < len) ? scores[srow + s] : -3.0e38f;
    float m = sc;
    m = fmaxf(m, __shfl_xor(m, 1));  m = fmaxf(m, __shfl_xor(m, 2));
    m = fmaxf(m, __shfl_xor(m, 4));  m = fmaxf(m, __shfl_xor(m, 8));
    m = fmaxf(m, __shfl_xor(m, 16)); m = fmaxf(m, __shfl_xor(m, 32));
    if (lane == 0) red[wave] = m;
    __syncthreads();
    if (s == 0) bc = fmaxf(fmaxf(red[0], red[1]), fmaxf(red[2], red[3]));
    __syncthreads();
    const float mx = bc;
    float e = (s < len) ? __expf(sc - mx) : 0.f;
    float sum = e;
    sum += __shfl_xor(sum, 1);  sum += __shfl_xor(sum, 2);
    sum += __shfl_xor(sum, 4);  sum += __shfl_xor(sum, 8);
    sum += __shfl_xor(sum, 16); sum += __shfl_xor(sum, 32);
    __syncthreads();
    if (lane == 0) red[wave] = sum;
    __syncthreads();
    if (s == 0) bc = red[0] + red[1] + red[2] + red[3];
    __syncthreads();
    const float p = e / bc;
    probf[(long long)n * S + s] = p;
    probb[srow + s] = f2bf(p);
}

__global__ __launch_bounds__(256) void sw_kernel(
    const float* __restrict__ hf32, const float* __restrict__ ctx,
    const u16* __restrict__ decin, const float* __restrict__ Wr,
    const float* __restrict__ br, float* __restrict__ sw, int t) {
    const int n = blockIdx.x, b = n & 15, slot = n >> 4;
    const int tid = threadIdx.x, lane = tid & 63, wave = tid >> 6;
    __shared__ float red[4];
    float p = 0.f;
    const float* hrow = hf32 + (long long)n * H;
    const float* crow = ctx + ((long long)(b * NSLOT + slot)) * H;
    const u16*  xrow = decin + ((long long)t * NB + n) * H;
    for (int k = tid; k < H; k += 256)
        p += hrow[k] * Wr[k] + crow[k] * Wr[H + k] + bf2f(xrow[k]) * Wr[2 * H + k];
    p += __shfl_xor(p, 1);  p += __shfl_xor(p, 2);
    p += __shfl_xor(p, 4);  p += __shfl_xor(p, 8);
    p += __shfl_xor(p, 16); p += __shfl_xor(p, 32);
    if (lane == 0) red[wave] = p;
    __syncthreads();
    if (tid == 0) {
        float v = red[0] + red[1] + red[2] + red[3] + br[0];
        sw[n] = 1.f / (1.f + __expf(-v));
    }
}

__global__ void scale_kernel(float* __restrict__ out, const float* __restrict__ sw,
                             const float* __restrict__ rowsum, int t) {
    const int n = blockIdx.x;
    const float f = sw[n] / rowsum[n];
    float* row = out + ((long long)n * T + t) * V;
    const int col = blockIdx.y * 256 + threadIdx.x;
    if (col < V) row[col] *= f;
}

__global__ void scatter_kernel(float* __restrict__ out, const int* __restrict__ story,
                               const int* __restrict__ lens, const float* __restrict__ sw,
                               const float* __restrict__ probf, int t) {
    const int n = blockIdx.x, b = n & 15, s = threadIdx.x;
    if (s < lens[b]) {
        int tok = story[b * S + s];
        atomicAdd(out + ((long long)n * T + t) * V + tok,
                  (1.f - sw[n]) * probf[(long long)n * S + s]);
    }
}

__global__ __launch_bounds__(64) void gate_kernel(const float* __restrict__ ctx,
                                                  const float* __restrict__ Wg,
                                                  const float* __restrict__ bg,
                                                  float* __restrict__ gout) {
    const int n = blockIdx.x, b = n & 15, slot = n >> 4, lane = threadIdx.x;
    const float* crow = ctx + ((long long)(b * NSLOT + slot)) * H;
    for (int g = 0; g < G; ++g) {
        float p = 0.f;
        for (int k = lane; k < H; k += 64) p += crow[k] * Wg[g * H + k];
        p += __shfl_xor(p, 1);  p += __shfl_xor(p, 2);
        p += __shfl_xor(p, 4);  p += __shfl_xor(p, 8);
        p += __shfl_xor(p, 16); p += __shfl_xor(p, 32);
        if (lane == 0) gout[(long long)n * G + g] = p + bg[g];
    }
}

// ---------------------------------------------------------------------------
extern "C" void kernel_launch(void* const* d_in, const int* in_sizes, int n_in,
                              void* d_out, int out_size, void* d_ws, size_t ws_size,
                              hipStream_t stream) {
    const int*   story = (const int*)d_in[0];
    const int*   lens  = (const int*)d_in[1];
    const int*   tgt   = (const int*)d_in[2];
    const int*   dom   = (const int*)d_in[3];
    const int*   sidx  = (const int*)d_in[4];
    const float* emb   = (const float*)d_in[5];
    const float* wihf  = (const float*)d_in[6];
    const float* whhf  = (const float*)d_in[7];
    const float* bihf  = (const float*)d_in[8];
    const float* bhhf  = (const float*)d_in[9];
    const float* wihb  = (const float*)d_in[10];
    const float* whhb  = (const float*)d_in[11];
    const float* bihb  = (const float*)d_in[12];
    const float* bhhb  = (const float*)d_in[13];
    const float* dwih  = (const float*)d_in[14];
    const float* dwhh  = (const float*)d_in[15];
    const float* dbih  = (const float*)d_in[16];
    const float* dbhh  = (const float*)d_in[17];
    const float* Wr    = (const float*)d_in[18];
    const float* br    = (const float*)d_in[19];
    const float* Wg    = (const float*)d_in[20];
    const float* bg    = (const float*)d_in[21];
    const float* slt   = (const float*)d_in[22];
    float* out = (float*)d_out;

    char* wsb = (char*)d_ws;
    size_t off = 0;
    auto alloc = [&](size_t bytes) -> char* {
        char* p = wsb + off;
        off += (bytes + 255) & ~(size_t)255;
        return p;
    };
    u16*   embb   = (u16*)alloc((size_t)V * H * 2);
    u16*   wihfb  = (u16*)alloc((size_t)H3 * H * 2);
    u16*   wihbb  = (u16*)alloc((size_t)H3 * H * 2);
    u16*   dwihb  = (u16*)alloc((size_t)H3 * H * 2);
    u16*   dwhhb  = (u16*)alloc((size_t)H3 * H * 2);
    u16*   wencp  = (u16*)alloc((size_t)2 * ENBLK * EROWS * EKP * 2);
    u16*   hbuf   = (u16*)alloc((size_t)2 * 2 * B * HROW * 2);
    int*   flags  = (int*)alloc((size_t)2 * ENBLK * 4);
    u16*   xb     = (u16*)alloc((size_t)S * B * H * 2);
    u16*   decinb = (u16*)alloc((size_t)T * NB * H * 2);
    float* gif    = (float*)alloc((size_t)S * B * H3 * 4);
    float* gib    = (float*)alloc((size_t)S * B * H3 * 4);
    float* dgi    = (float*)alloc((size_t)T * NB * H3 * 4);
    float* ysf    = (float*)alloc((size_t)B * S * H * 4);
    float* ysb    = (float*)alloc((size_t)B * S * H * 4);
    float* hfv    = (float*)alloc((size_t)B * H * 4);
    float* hbv    = (float*)alloc((size_t)B * H * 4);
    u16*   Eb     = (u16*)alloc((size_t)B * S * H * 2);
    u16*   ETb    = (u16*)alloc((size_t)B * H * S * 2);
    float* hf32   = (float*)alloc((size_t)NB * H * 4);
    u16*   hnk    = (u16*)alloc((size_t)NB * H * 2);
    u16*   hbsk   = (u16*)alloc((size_t)NB * H * 2);
    float* dgh    = (float*)alloc((size_t)NB * H3 * 4);
    float* scores = (float*)alloc((size_t)NB * S * 4);
    float* probf  = (float*)alloc((size_t)NB * S * 4);
    u16*   probb  = (u16*)alloc((size_t)NB * S * 2);
    float* ctx    = (float*)alloc((size_t)NB * H * 4);
    float* swv    = (float*)alloc((size_t)NB * 4);
    float* rowsum = (float*)alloc((size_t)NB * 4);
    (void)ws_size; (void)in_sizes; (void)n_in; (void)out_size;

    auto launch_gemm = [&](const u16* A, const u16* Bt, const float* bias, float* C,
                           int M, int N, int K, int lda, int ldb, long long ldc,
                           long long sA, long long sB, long long sC, int nb,
                           int mode, float* rs) {
        dim3 g((M + 63) / 64, (N + 63) / 64, nb);
        gemm_bt<<<g, 256, 0, stream>>>(A, Bt, bias, C, M, N, K, lda, ldb, ldc,
                                       sA, sB, sC, mode, rs);
    };

    // ---- setup: casts, embeddings, input-side GEMMs -----------------------
    cvt_bf16_kernel<<<2048, 256, 0, stream>>>(emb, embb, V * H);
    cvt_bf16_kernel<<<512, 256, 0, stream>>>(wihf, wihfb, H3 * H);
    cvt_bf16_kernel<<<512, 256, 0, stream>>>(wihb, wihbb, H3 * H);
    cvt_bf16_kernel<<<512, 256, 0, stream>>>(dwih, dwihb, H3 * H);
    cvt_bf16_kernel<<<512, 256, 0, stream>>>(dwhh, dwhhb, H3 * H);
    {
        const int total = 2 * ENBLK * EROWS * EKP;
        prep_wenc_kernel<<<(total + 255) / 256, 256, 0, stream>>>(whhf, whhb, wencp);
    }
    embed_story_kernel<<<S * B, 256, 0, stream>>>(story, embb, xb);
    { dim3 g(NB, T); build_decin_kernel<<<g, 256, 0, stream>>>(tgt, dom, sidx, slt, embb, decinb); }

    launch_gemm(xb, wihfb, bihf, gif, S * B, H3, H, H, H, H3, 0, 0, 0, 1, 0, nullptr);
    launch_gemm(xb, wihbb, bihb, gib, S * B, H3, H, H, H, H3, 0, 0, 0, 1, 0, nullptr);
    launch_gemm(decinb, dwihb, dbih, dgi, T * NB, H3, H, H, H, H3, 0, 0, 0, 1, 0, nullptr);

    // ---- encoder recurrence (distributed, flag-synced) --------------------
    hipMemsetAsync(flags, 0, (size_t)2 * ENBLK * 4, stream);
    hipMemsetAsync(hbuf, 0, (size_t)2 * 2 * B * HROW * 2, stream);
    enc_rnn2_kernel<<<2 * ENBLK, 256, 0, stream>>>(wencp, bhhf, bhhb, gif, gib, lens,
                                                   hbuf, flags, ysf, ysb, hfv, hbv);
    { dim3 g(B, S / 32); packE_kernel<<<g, 256, 0, stream>>>(ysf, ysb, Eb, ETb); }
    h0_kernel<<<NB, 256, 0, stream>>>(hfv, hbv, hf32, hnk, hbsk);

    // ---- decoder ----------------------------------------------------------
    for (int t = 0; t < T; ++t) {
        launch_gemm(hnk, dwhhb, dbhh, dgh, NB, H3, H, H, H, H3, 0, 0, 0, 1, 0, nullptr);
        dec_gru_kernel<<<NB, 256, 0, stream>>>(dgi, dgh, hf32, hnk, hbsk, t);
        launch_gemm(hbsk, Eb, nullptr, scores, NSLOT, S, H, H, H, S,
                    (long long)NSLOT * H, (long long)S * H, (long long)NSLOT * S, B, 0, nullptr);
        attn_softmax_kernel<<<NB, 256, 0, stream>>>(scores, lens, probf, probb);
        launch_gemm(probb, ETb, nullptr, ctx, NSLOT, H, S, S, S, H,
                    (long long)NSLOT * S, (long long)H * S, (long long)NSLOT * H, B, 0, nullptr);
        if (t == 0)
            gate_kernel<<<NB, 64, 0, stream>>>(ctx, Wg, bg, out + (size_t)NB * T * V);
        sw_kernel<<<NB, 256, 0, stream>>>(hf32, ctx, decinb, Wr, br, swv, t);
        hipMemsetAsync(rowsum, 0, NB * sizeof(float), stream);
        launch_gemm(hnk, embb, nullptr, out + (size_t)t * V, NB, V, H, H, H,
                    (long long)T * V, 0, 0, 0, 1, 1, rowsum);
        { dim3 g(NB, (V + 255) / 256); scale_kernel<<<g, 256, 0, stream>>>(out, swv, rowsum, t); }
        scatter_kernel<<<NB, 256, 0, stream>>>(out, story, lens, swv, probf, t);
    }
}

// Round 3
// 3629.507 us; speedup vs baseline: 2.3043x; 1.0688x over previous
//
#include <hip/hip_runtime.h>
#include <hip/hip_bf16.h>

typedef unsigned short u16;
typedef __attribute__((ext_vector_type(8))) short bf16x8;
typedef __attribute__((ext_vector_type(4))) float f32x4;
typedef __attribute__((ext_vector_type(4))) unsigned u32x4;

static constexpr int V = 20000, H = 400, B = 16, S = 256, NSLOT = 30, T = 10, G = 3;
static constexpr int H3 = 3 * H;           // 1200
static constexpr int NB = NSLOT * B;       // 480
// encoder partition
static constexpr int ENBLK = 20;           // blocks per direction
static constexpr int ESL   = 20;           // h components per block (400/20)
static constexpr int EROWS = 64;           // padded weight rows per block (3*20 -> 64)
static constexpr int EKP   = 416;          // padded K (400 -> 416)

__device__ __forceinline__ float bf2f(u16 v) {
    union { unsigned u; float f; } x; x.u = ((unsigned)v) << 16; return x.f;
}
__device__ __forceinline__ u16 f2bf(float f) {
    union { float f; unsigned u; } x; x.f = f;
    unsigned r = x.u + 0x7fffu + ((x.u >> 16) & 1u);   // round-to-nearest-even
    return (u16)(r >> 16);
}

// ---------------------------------------------------------------------------
// Generic batched GEMM: C[m][n] = sum_k A[m][k] * Bt[n][k]  (+bias[n])
// mode 0: plain (+bias). mode 1: C=exp(acc), atomicAdd row sums (softmax num).
// ---------------------------------------------------------------------------
__global__ __launch_bounds__(256) void gemm_bt(
    const u16* __restrict__ A, const u16* __restrict__ Bt,
    const float* __restrict__ bias, float* __restrict__ C,
    int M, int N, int K, int lda, int ldb, long long ldc,
    long long sA, long long sB, long long sC,
    int mode, float* __restrict__ rowsum)
{
    __shared__ u16 As[64][40];
    __shared__ u16 Bs[64][40];
    const int bz = blockIdx.z;
    A  += (long long)bz * sA;
    Bt += (long long)bz * sB;
    C  += (long long)bz * sC;
    const int m0 = blockIdx.x * 64, n0 = blockIdx.y * 64;
    const int tid = threadIdx.x, wave = tid >> 6, lane = tid & 63;
    const int wm = (wave >> 1) * 32, wn = (wave & 1) * 32;
    const int srow = tid >> 2, scol = (tid & 3) * 8;
    const int fr = lane & 15, kq = lane >> 4;
    f32x4 acc[2][2];
#pragma unroll
    for (int i = 0; i < 2; ++i)
#pragma unroll
        for (int j = 0; j < 2; ++j) acc[i][j] = (f32x4){0.f, 0.f, 0.f, 0.f};

    for (int k0 = 0; k0 < K; k0 += 32) {
        {
            int gr = m0 + srow, gc = k0 + scol;
            bf16x8 v;
            if (gr < M && gc + 8 <= K) {
                v = *(const bf16x8*)(A + (long long)gr * lda + gc);
            } else {
                short tmp[8];
#pragma unroll
                for (int j = 0; j < 8; ++j)
                    tmp[j] = (gr < M && gc + j < K) ? (short)A[(long long)gr * lda + gc + j] : (short)0;
                v = *(bf16x8*)tmp;
            }
            *(bf16x8*)&As[srow][scol] = v;
        }
        {
            int gr = n0 + srow, gc = k0 + scol;
            bf16x8 v;
            if (gr < N && gc + 8 <= K) {
                v = *(const bf16x8*)(Bt + (long long)gr * ldb + gc);
            } else {
                short tmp[8];
#pragma unroll
                for (int j = 0; j < 8; ++j)
                    tmp[j] = (gr < N && gc + j < K) ? (short)Bt[(long long)gr * ldb + gc + j] : (short)0;
                v = *(bf16x8*)tmp;
            }
            *(bf16x8*)&Bs[srow][scol] = v;
        }
        __syncthreads();
        bf16x8 af[2], bfr[2];
#pragma unroll
        for (int i = 0; i < 2; ++i) af[i]  = *(const bf16x8*)&As[wm + i * 16 + fr][kq * 8];
#pragma unroll
        for (int j = 0; j < 2; ++j) bfr[j] = *(const bf16x8*)&Bs[wn + j * 16 + fr][kq * 8];
#pragma unroll
        for (int i = 0; i < 2; ++i)
#pragma unroll
            for (int j = 0; j < 2; ++j)
                acc[i][j] = __builtin_amdgcn_mfma_f32_16x16x32_bf16(af[i], bfr[j], acc[i][j], 0, 0, 0);
        __syncthreads();
    }

#pragma unroll
    for (int i = 0; i < 2; ++i)
#pragma unroll
        for (int j = 0; j < 2; ++j) {
            int col = n0 + wn + j * 16 + fr;
            float bv = (bias != nullptr && col < N) ? bias[col] : 0.f;
#pragma unroll
            for (int r = 0; r < 4; ++r) {
                int row = m0 + wm + i * 16 + kq * 4 + r;
                bool ok = (row < M) && (col < N);
                float v = acc[i][j][r] + bv;
                if (mode == 1) { v = ok ? __expf(v) : 0.f; acc[i][j][r] = v; }
                if (ok) C[(long long)row * ldc + col] = v;
            }
        }
    if (mode == 1) {
#pragma unroll
        for (int i = 0; i < 2; ++i)
#pragma unroll
            for (int r = 0; r < 4; ++r) {
                float s = acc[i][0][r] + acc[i][1][r];
                s += __shfl_xor(s, 1); s += __shfl_xor(s, 2);
                s += __shfl_xor(s, 4); s += __shfl_xor(s, 8);
                if (fr == 0) {
                    int row = m0 + wm + i * 16 + kq * 4 + r;
                    if (row < M) atomicAdd(&rowsum[row], s);
                }
            }
    }
}

// ---------------------------------------------------------------------------
// small utility kernels
// ---------------------------------------------------------------------------
__global__ void cvt_bf16_kernel(const float* __restrict__ src, u16* __restrict__ dst, int n) {
    for (int i = blockIdx.x * blockDim.x + threadIdx.x; i < n; i += gridDim.x * blockDim.x)
        dst[i] = f2bf(src[i]);
}

// weight prep for the distributed encoder: dst[dir][j][rloc][k], rloc = g*20+c
__global__ void prep_wenc_kernel(const float* __restrict__ whhf, const float* __restrict__ whhb,
                                 u16* __restrict__ dst) {
    int idx = blockIdx.x * 256 + threadIdx.x;
    const int total = 2 * ENBLK * EROWS * EKP;
    if (idx >= total) return;
    int k = idx % EKP; int r = idx / EKP;
    int rloc = r % EROWS; r /= EROWS;
    int j = r % ENBLK; int dir = r / ENBLK;
    u16 v = 0;
    if (k < H && rloc < 3 * ESL) {
        int g = rloc / ESL, c = rloc % ESL;
        const float* W = dir ? whhb : whhf;
        v = f2bf(W[(long long)(g * H + j * ESL + c) * H + k]);
    }
    dst[idx] = v;
}

__global__ void embed_story_kernel(const int* __restrict__ story, const u16* __restrict__ embb,
                                   u16* __restrict__ xb) {
    int row = blockIdx.x;                 // row = s*16 + b
    int s = row >> 4, b = row & 15;
    int tok = story[b * S + s];
    const u16* e = embb + (long long)tok * H;
    u16* d = xb + (long long)row * H;
    for (int k = threadIdx.x; k < H; k += blockDim.x) d[k] = e[k];
}

__global__ void build_decin_kernel(const int* __restrict__ tgt, const int* __restrict__ dom,
                                   const int* __restrict__ sidx, const float* __restrict__ slt,
                                   const u16* __restrict__ embb, u16* __restrict__ decin) {
    int n = blockIdx.x, t = blockIdx.y;
    int b = n & 15, slot = n >> 4;
    u16* d = decin + ((long long)t * NB + n) * H;
    if (t == 0) {
        const float* s1 = slt + (long long)dom[slot] * H;
        const float* s2 = slt + (long long)sidx[slot] * H;
        for (int k = threadIdx.x; k < H; k += blockDim.x) d[k] = f2bf(s1[k] + s2[k]);
    } else {
        int tok = tgt[(b * NSLOT + slot) * T + (t - 1)];
        const u16* e = embb + (long long)tok * H;
        for (int k = threadIdx.x; k < H; k += blockDim.x) d[k] = e[k];
    }
}

// ---------------------------------------------------------------------------
// Distributed encoder recurrence: 40 blocks = 2 dirs x 20 slices.
// Protocol v2: relaxed agent-scope spin (no per-poll invalidate) + single
// acquire fence; h published as packed (hi|lo<<16) u32 via relaxed agent
// atomic stores (write-through); readers unpack with v_perm_b32.
// ---------------------------------------------------------------------------
__global__ __launch_bounds__(256) void enc_rnn2_kernel(
    const u16* __restrict__ wencp,
    const float* __restrict__ bhhf, const float* __restrict__ bhhb,
    const float* __restrict__ gif, const float* __restrict__ gib,
    const int* __restrict__ lens,
    unsigned* __restrict__ hbuf, int* __restrict__ flags,
    float* __restrict__ ysf, float* __restrict__ ysb,
    float* __restrict__ hfo, float* __restrict__ hbo)
{
    const int bid = blockIdx.x;
    const int dir = bid / ENBLK, j = bid % ENBLK;
    const float* bhh = dir ? bhhb : bhhf;
    const float* gi  = dir ? gib  : gif;
    float* ys = dir ? ysb : ysf;
    float* ho = dir ? hbo : hfo;

    __shared__ u16 wlds[EROWS * EKP];      // 53248 B
    __shared__ float ghs[EROWS * 17];      // 4352 B

    const int tid = threadIdx.x, wave = tid >> 6, lane = tid & 63;
    const int fr = lane & 15, kq = lane >> 4;

    const u16* wsrc = wencp + (long long)(dir * ENBLK + j) * EROWS * EKP;
    for (int i = tid * 8; i < EROWS * EKP; i += 256 * 8)
        *(bf16x8*)&wlds[i] = *(const bf16x8*)&wsrc[i];
    for (int i = tid; i < EROWS * 17; i += 256) ghs[i] = 0.f;

    const int p0 = tid, p1 = 256 + tid;
    const bool has1 = (tid < 64);
    const int b0 = p0 / ESL, kl0 = p0 % ESL;
    const int b1 = has1 ? p1 / ESL : 0, kl1 = has1 ? p1 % ESL : 0;
    const int k0 = j * ESL;
    const int len0 = lens[b0];
    const int len1 = has1 ? lens[b1] : 0;
    const float bhr0 = bhh[k0 + kl0], bhz0 = bhh[H + k0 + kl0], bhn0 = bhh[2 * H + k0 + kl0];
    const float bhr1 = has1 ? bhh[k0 + kl1] : 0.f;
    const float bhz1 = has1 ? bhh[H + k0 + kl1] : 0.f;
    const float bhn1 = has1 ? bhh[2 * H + k0 + kl1] : 0.f;
    float h0r = 0.f, h1r = 0.f;

    const int fbase = dir * ENBLK;
    unsigned* hb_d = hbuf + (long long)dir * 2 * B * EKP;
    const u16* arow = &wlds[(wave * 16 + fr) * EKP + kq * 8];
    __syncthreads();

    for (int t = 0; t < S; ++t) {
        const int s = dir ? (S - 1 - t) : t;
        const float* gbase = gi + (long long)s * B * H3;
        float gr0 = gbase[b0 * H3 + k0 + kl0];
        float gz0 = gbase[b0 * H3 + H + k0 + kl0];
        float gn0 = gbase[b0 * H3 + 2 * H + k0 + kl0];
        float gr1 = 0.f, gz1 = 0.f, gn1 = 0.f;
        if (has1) {
            gr1 = gbase[b1 * H3 + k0 + kl1];
            gz1 = gbase[b1 * H3 + H + k0 + kl1];
            gn1 = gbase[b1 * H3 + 2 * H + k0 + kl1];
        }

        f32x4 acc = (f32x4){0.f, 0.f, 0.f, 0.f};
        if (t > 0) {
            // relaxed spin (sc1 load, no cache maintenance) + backoff
            for (;;) {
                int v = 0x7fffffff;
                if (lane < ENBLK)
                    v = __hip_atomic_load(&flags[fbase + lane], __ATOMIC_RELAXED,
                                          __HIP_MEMORY_SCOPE_AGENT);
                if (__all(v >= t)) break;
                __builtin_amdgcn_s_sleep(2);
            }
            // one acquire fence: invalidate stale L2 lines before reading hbuf
            __builtin_amdgcn_fence(__ATOMIC_ACQUIRE, "agent");
            const unsigned* hrow = hb_d + (long long)(t & 1) * B * EKP
                                   + (long long)fr * EKP + kq * 8;
            f32x4 acch = (f32x4){0.f, 0.f, 0.f, 0.f};
            f32x4 accl = (f32x4){0.f, 0.f, 0.f, 0.f};
#pragma unroll
            for (int kk = 0; kk < 13; ++kk) {
                u32x4 a = *(const u32x4*)(hrow + kk * 32);
                u32x4 b = *(const u32x4*)(hrow + kk * 32 + 4);
                union { unsigned u[4]; bf16x8 v; } hi, lo;
                hi.u[0] = __builtin_amdgcn_perm(a[1], a[0], 0x05040100u);
                hi.u[1] = __builtin_amdgcn_perm(a[3], a[2], 0x05040100u);
                hi.u[2] = __builtin_amdgcn_perm(b[1], b[0], 0x05040100u);
                hi.u[3] = __builtin_amdgcn_perm(b[3], b[2], 0x05040100u);
                lo.u[0] = __builtin_amdgcn_perm(a[1], a[0], 0x07060302u);
                lo.u[1] = __builtin_amdgcn_perm(a[3], a[2], 0x07060302u);
                lo.u[2] = __builtin_amdgcn_perm(b[1], b[0], 0x07060302u);
                lo.u[3] = __builtin_amdgcn_perm(b[3], b[2], 0x07060302u);
                bf16x8 av = *(const bf16x8*)(arow + kk * 32);
                acch = __builtin_amdgcn_mfma_f32_16x16x32_bf16(av, hi.v, acch, 0, 0, 0);
                accl = __builtin_amdgcn_mfma_f32_16x16x32_bf16(av, lo.v, accl, 0, 0, 0);
            }
            acc = acch + accl;
        }
#pragma unroll
        for (int r = 0; r < 4; ++r) ghs[(wave * 16 + kq * 4 + r) * 17 + fr] = acc[r];
        __syncthreads();

        unsigned* hpub = hb_d + (long long)((t + 1) & 1) * B * EKP;
        {
            float ghr = ghs[kl0 * 17 + b0];
            float ghz = ghs[(ESL + kl0) * 17 + b0];
            float ghn = ghs[(2 * ESL + kl0) * 17 + b0];
            float rg = 1.f / (1.f + __expf(-(gr0 + ghr + bhr0)));
            float zg = 1.f / (1.f + __expf(-(gz0 + ghz + bhz0)));
            float ng = tanhf(gn0 + rg * (ghn + bhn0));
            float hn = (1.f - zg) * ng + zg * h0r;
            bool msk = s < len0;
            float y = msk ? hn : 0.f;
            if (msk) h0r = hn;
            ys[((long long)(b0 * S + s)) * H + k0 + kl0] = y;
            u16 hi = f2bf(h0r);
            unsigned packed = (unsigned)hi | ((unsigned)f2bf(h0r - bf2f(hi)) << 16);
            __hip_atomic_store(&hpub[b0 * EKP + k0 + kl0], packed, __ATOMIC_RELAXED,
                               __HIP_MEMORY_SCOPE_AGENT);
        }
        if (has1) {
            float ghr = ghs[kl1 * 17 + b1];
            float ghz = ghs[(ESL + kl1) * 17 + b1];
            float ghn = ghs[(2 * ESL + kl1) * 17 + b1];
            float rg = 1.f / (1.f + __expf(-(gr1 + ghr + bhr1)));
            float zg = 1.f / (1.f + __expf(-(gz1 + ghz + bhz1)));
            float ng = tanhf(gn1 + rg * (ghn + bhn1));
            float hn = (1.f - zg) * ng + zg * h1r;
            bool msk = s < len1;
            float y = msk ? hn : 0.f;
            if (msk) h1r = hn;
            ys[((long long)(b1 * S + s)) * H + k0 + kl1] = y;
            u16 hi = f2bf(h1r);
            unsigned packed = (unsigned)hi | ((unsigned)f2bf(h1r - bf2f(hi)) << 16);
            __hip_atomic_store(&hpub[b1 * EKP + k0 + kl1], packed, __ATOMIC_RELAXED,
                               __HIP_MEMORY_SCOPE_AGENT);
        }
        // barrier waits each wave's vmcnt(0): publish stores reached coherent pt
        __syncthreads();
        if (tid == 0)
            __hip_atomic_store(&flags[fbase + j], t + 1, __ATOMIC_RELEASE,
                               __HIP_MEMORY_SCOPE_AGENT);
    }
    ho[b0 * H + k0 + kl0] = h0r;
    if (has1) ho[b1 * H + k0 + kl1] = h1r;
}

// E = ys_f + ys_b (bf16, [b][s][k]) and ET (bf16, [b][k][s])
__global__ void packE_kernel(const float* __restrict__ ysf, const float* __restrict__ ysb,
                             u16* __restrict__ E, u16* __restrict__ ET) {
    __shared__ u16 tile[32][400];
    const int b = blockIdx.x, s0 = blockIdx.y * 32;
    for (int si = 0; si < 32; ++si) {
        const long long base = ((long long)b * S + s0 + si) * H;
        for (int k = threadIdx.x; k < H; k += blockDim.x) {
            u16 v = f2bf(ysf[base + k] + ysb[base + k]);
            E[base + k] = v;
            tile[si][k] = v;
        }
    }
    __syncthreads();
    for (int idx = threadIdx.x; idx < 32 * H; idx += blockDim.x) {
        int k = idx >> 5, si = idx & 31;
        ET[((long long)b * H + k) * S + s0 + si] = tile[si][k];
    }
}

__global__ void h0_kernel(const float* __restrict__ hf, const float* __restrict__ hb,
                          float* __restrict__ hf32, u16* __restrict__ hnk, u16* __restrict__ hbsk) {
    int n = blockIdx.x, b = n & 15, slot = n >> 4;
    for (int k = threadIdx.x; k < H; k += blockDim.x) {
        float v = hf[b * H + k] + hb[b * H + k];
        hf32[(long long)n * H + k] = v;
        u16 bv = f2bf(v);
        hnk[(long long)n * H + k] = bv;
        hbsk[((long long)(b * NSLOT + slot)) * H + k] = bv;
    }
}

__global__ void dec_gru_kernel(const float* __restrict__ dgi, const float* __restrict__ dgh,
                               float* __restrict__ hf32, u16* __restrict__ hnk,
                               u16* __restrict__ hbsk, int t) {
    int n = blockIdx.x, b = n & 15, slot = n >> 4;
    const float* gi = dgi + ((long long)t * NB + n) * H3;
    const float* gh = dgh + (long long)n * H3;
    for (int k = threadIdx.x; k < H; k += blockDim.x) {
        float r  = 1.f / (1.f + __expf(-(gi[k]         + gh[k])));
        float z  = 1.f / (1.f + __expf(-(gi[H + k]     + gh[H + k])));
        float nn = tanhf(gi[2 * H + k] + r * gh[2 * H + k]);
        float h  = hf32[(long long)n * H + k];
        float hn = (1.f - z) * nn + z * h;
        hf32[(long long)n * H + k] = hn;
        u16 bv = f2bf(hn);
        hnk[(long long)n * H + k] = bv;
        hbsk[((long long)(b * NSLOT + slot)) * H + k] = bv;
    }
}

__global__ __launch_bounds__(256) void attn_softmax_kernel(
    const float* __restrict__ scores, const int* __restrict__ lens,
    float* __restrict__ probf, u16* __restrict__ probb) {
    const int n = blockIdx.x, b = n & 15, slot = n >> 4;
    const int s = threadIdx.x, lane = s & 63, wave = s >> 6;
    const int len = lens[b];
    __shared__ float red[4];
    __shared__ float bc;
    const long long srow = ((long long)(b * NSLOT + slot)) * S;
    float sc = (s < len) ? scores[srow + s] : -3.0e38f;
    float m = sc;
    m = fmaxf(m, __shfl_xor(m, 1));  m = fmaxf(m, __shfl_xor(m, 2));
    m = fmaxf(m, __shfl_xor(m, 4));  m = fmaxf(m, __shfl_xor(m, 8));
    m = fmaxf(m, __shfl_xor(m, 16)); m = fmaxf(m, __shfl_xor(m, 32));
    if (lane == 0) red[wave] = m;
    __syncthreads();
    if (s == 0) bc = fmaxf(fmaxf(red[0], red[1]), fmaxf(red[2], red[3]));
    __syncthreads();
    const float mx = bc;
    float e = (s < len) ? __expf(sc - mx) : 0.f;
    float sum = e;
    sum += __shfl_xor(sum, 1);  sum += __shfl_xor(sum, 2);
    sum += __shfl_xor(sum, 4);  sum += __shfl_xor(sum, 8);
    sum += __shfl_xor(sum, 16); sum += __shfl_xor(sum, 32);
    __syncthreads();
    if (lane == 0) red[wave] = sum;
    __syncthreads();
    if (s == 0) bc = red[0] + red[1] + red[2] + red[3];
    __syncthreads();
    const float p = e / bc;
    probf[(long long)n * S + s] = p;
    probb[srow + s] = f2bf(p);
}

__global__ __launch_bounds__(256) void sw_kernel(
    const float* __restrict__ hf32, const float* __restrict__ ctx,
    const u16* __restrict__ decin, const float* __restrict__ Wr,
    const float* __restrict__ br, float* __restrict__ sw, int t) {
    const int n = blockIdx.x, b = n & 15, slot = n >> 4;
    const int tid = threadIdx.x, lane = tid & 63, wave = tid >> 6;
    __shared__ float red[4];
    float p = 0.f;
    const float* hrow = hf32 + (long long)n * H;
    const float* crow = ctx + ((long long)(b * NSLOT + slot)) * H;
    const u16*  xrow = decin + ((long long)t * NB + n) * H;
    for (int k = tid; k < H; k += 256)
        p += hrow[k] * Wr[k] + crow[k] * Wr[H + k] + bf2f(xrow[k]) * Wr[2 * H + k];
    p += __shfl_xor(p, 1);  p += __shfl_xor(p, 2);
    p += __shfl_xor(p, 4);  p += __shfl_xor(p, 8);
    p += __shfl_xor(p, 16); p += __shfl_xor(p, 32);
    if (lane == 0) red[wave] = p;
    __syncthreads();
    if (tid == 0) {
        float v = red[0] + red[1] + red[2] + red[3] + br[0];
        sw[n] = 1.f / (1.f + __expf(-v));
    }
}

__global__ void scale_kernel(float* __restrict__ out, const float* __restrict__ sw,
                             const float* __restrict__ rowsum, int t) {
    const int n = blockIdx.x;
    const float f = sw[n] / rowsum[n];
    float* row = out + ((long long)n * T + t) * V;
    const int col = blockIdx.y * 256 + threadIdx.x;
    if (col < V) row[col] *= f;
}

__global__ void scatter_kernel(float* __restrict__ out, const int* __restrict__ story,
                               const int* __restrict__ lens, const float* __restrict__ sw,
                               const float* __restrict__ probf, int t) {
    const int n = blockIdx.x, b = n & 15, s = threadIdx.x;
    if (s < lens[b]) {
        int tok = story[b * S + s];
        atomicAdd(out + ((long long)n * T + t) * V + tok,
                  (1.f - sw[n]) * probf[(long long)n * S + s]);
    }
}

__global__ __launch_bounds__(64) void gate_kernel(const float* __restrict__ ctx,
                                                  const float* __restrict__ Wg,
                                                  const float* __restrict__ bg,
                                                  float* __restrict__ gout) {
    const int n = blockIdx.x, b = n & 15, slot = n >> 4, lane = threadIdx.x;
    const float* crow = ctx + ((long long)(b * NSLOT + slot)) * H;
    for (int g = 0; g < G; ++g) {
        float p = 0.f;
        for (int k = lane; k < H; k += 64) p += crow[k] * Wg[g * H + k];
        p += __shfl_xor(p, 1);  p += __shfl_xor(p, 2);
        p += __shfl_xor(p, 4);  p += __shfl_xor(p, 8);
        p += __shfl_xor(p, 16); p += __shfl_xor(p, 32);
        if (lane == 0) gout[(long long)n * G + g] = p + bg[g];
    }
}

// ---------------------------------------------------------------------------
extern "C" void kernel_launch(void* const* d_in, const int* in_sizes, int n_in,
                              void* d_out, int out_size, void* d_ws, size_t ws_size,
                              hipStream_t stream) {
    const int*   story = (const int*)d_in[0];
    const int*   lens  = (const int*)d_in[1];
    const int*   tgt   = (const int*)d_in[2];
    const int*   dom   = (const int*)d_in[3];
    const int*   sidx  = (const int*)d_in[4];
    const float* emb   = (const float*)d_in[5];
    const float* wihf  = (const float*)d_in[6];
    const float* whhf  = (const float*)d_in[7];
    const float* bihf  = (const float*)d_in[8];
    const float* bhhf  = (const float*)d_in[9];
    const float* wihb  = (const float*)d_in[10];
    const float* whhb  = (const float*)d_in[11];
    const float* bihb  = (const float*)d_in[12];
    const float* bhhb  = (const float*)d_in[13];
    const float* dwih  = (const float*)d_in[14];
    const float* dwhh  = (const float*)d_in[15];
    const float* dbih  = (const float*)d_in[16];
    const float* dbhh  = (const float*)d_in[17];
    const float* Wr    = (const float*)d_in[18];
    const float* br    = (const float*)d_in[19];
    const float* Wg    = (const float*)d_in[20];
    const float* bg    = (const float*)d_in[21];
    const float* slt   = (const float*)d_in[22];
    float* out = (float*)d_out;

    char* wsb = (char*)d_ws;
    size_t off = 0;
    auto alloc = [&](size_t bytes) -> char* {
        char* p = wsb + off;
        off += (bytes + 255) & ~(size_t)255;
        return p;
    };
    u16*   embb   = (u16*)alloc((size_t)V * H * 2);
    u16*   wihfb  = (u16*)alloc((size_t)H3 * H * 2);
    u16*   wihbb  = (u16*)alloc((size_t)H3 * H * 2);
    u16*   dwihb  = (u16*)alloc((size_t)H3 * H * 2);
    u16*   dwhhb  = (u16*)alloc((size_t)H3 * H * 2);
    u16*   wencp  = (u16*)alloc((size_t)2 * ENBLK * EROWS * EKP * 2);
    unsigned* hbuf = (unsigned*)alloc((size_t)2 * 2 * B * EKP * 4);
    int*   flags  = (int*)alloc((size_t)2 * ENBLK * 4);
    u16*   xb     = (u16*)alloc((size_t)S * B * H * 2);
    u16*   decinb = (u16*)alloc((size_t)T * NB * H * 2);
    float* gif    = (float*)alloc((size_t)S * B * H3 * 4);
    float* gib    = (float*)alloc((size_t)S * B * H3 * 4);
    float* dgi    = (float*)alloc((size_t)T * NB * H3 * 4);
    float* ysf    = (float*)alloc((size_t)B * S * H * 4);
    float* ysb    = (float*)alloc((size_t)B * S * H * 4);
    float* hfv    = (float*)alloc((size_t)B * H * 4);
    float* hbv    = (float*)alloc((size_t)B * H * 4);
    u16*   Eb     = (u16*)alloc((size_t)B * S * H * 2);
    u16*   ETb    = (u16*)alloc((size_t)B * H * S * 2);
    float* hf32   = (float*)alloc((size_t)NB * H * 4);
    u16*   hnk    = (u16*)alloc((size_t)NB * H * 2);
    u16*   hbsk   = (u16*)alloc((size_t)NB * H * 2);
    float* dgh    = (float*)alloc((size_t)NB * H3 * 4);
    float* scores = (float*)alloc((size_t)NB * S * 4);
    float* probf  = (float*)alloc((size_t)NB * S * 4);
    u16*   probb  = (u16*)alloc((size_t)NB * S * 2);
    float* ctx    = (float*)alloc((size_t)NB * H * 4);
    float* swv    = (float*)alloc((size_t)NB * 4);
    float* rowsumT = (float*)alloc((size_t)NB * T * 4);
    (void)ws_size; (void)in_sizes; (void)n_in; (void)out_size;

    auto launch_gemm = [&](const u16* A, const u16* Bt, const float* bias, float* C,
                           int M, int N, int K, int lda, int ldb, long long ldc,
                           long long sA, long long sB, long long sC, int nb,
                           int mode, float* rs) {
        dim3 g((M + 63) / 64, (N + 63) / 64, nb);
        gemm_bt<<<g, 256, 0, stream>>>(A, Bt, bias, C, M, N, K, lda, ldb, ldc,
                                       sA, sB, sC, mode, rs);
    };

    // ---- setup: casts, embeddings, input-side GEMMs -----------------------
    cvt_bf16_kernel<<<2048, 256, 0, stream>>>(emb, embb, V * H);
    cvt_bf16_kernel<<<512, 256, 0, stream>>>(wihf, wihfb, H3 * H);
    cvt_bf16_kernel<<<512, 256, 0, stream>>>(wihb, wihbb, H3 * H);
    cvt_bf16_kernel<<<512, 256, 0, stream>>>(dwih, dwihb, H3 * H);
    cvt_bf16_kernel<<<512, 256, 0, stream>>>(dwhh, dwhhb, H3 * H);
    {
        const int total = 2 * ENBLK * EROWS * EKP;
        prep_wenc_kernel<<<(total + 255) / 256, 256, 0, stream>>>(whhf, whhb, wencp);
    }
    embed_story_kernel<<<S * B, 256, 0, stream>>>(story, embb, xb);
    { dim3 g(NB, T); build_decin_kernel<<<g, 256, 0, stream>>>(tgt, dom, sidx, slt, embb, decinb); }

    launch_gemm(xb, wihfb, bihf, gif, S * B, H3, H, H, H, H3, 0, 0, 0, 1, 0, nullptr);
    launch_gemm(xb, wihbb, bihb, gib, S * B, H3, H, H, H, H3, 0, 0, 0, 1, 0, nullptr);
    launch_gemm(decinb, dwihb, dbih, dgi, T * NB, H3, H, H, H, H3, 0, 0, 0, 1, 0, nullptr);

    // ---- encoder recurrence (distributed, flag-synced) --------------------
    hipMemsetAsync(flags, 0, (size_t)2 * ENBLK * 4, stream);
    hipMemsetAsync(hbuf, 0, (size_t)2 * 2 * B * EKP * 4, stream);
    hipMemsetAsync(rowsumT, 0, (size_t)NB * T * 4, stream);
    enc_rnn2_kernel<<<2 * ENBLK, 256, 0, stream>>>(wencp, bhhf, bhhb, gif, gib, lens,
                                                   hbuf, flags, ysf, ysb, hfv, hbv);
    { dim3 g(B, S / 32); packE_kernel<<<g, 256, 0, stream>>>(ysf, ysb, Eb, ETb); }
    h0_kernel<<<NB, 256, 0, stream>>>(hfv, hbv, hf32, hnk, hbsk);

    // ---- decoder ----------------------------------------------------------
    for (int t = 0; t < T; ++t) {
        launch_gemm(hnk, dwhhb, dbhh, dgh, NB, H3, H, H, H, H3, 0, 0, 0, 1, 0, nullptr);
        dec_gru_kernel<<<NB, 256, 0, stream>>>(dgi, dgh, hf32, hnk, hbsk, t);
        launch_gemm(hbsk, Eb, nullptr, scores, NSLOT, S, H, H, H, S,
                    (long long)NSLOT * H, (long long)S * H, (long long)NSLOT * S, B, 0, nullptr);
        attn_softmax_kernel<<<NB, 256, 0, stream>>>(scores, lens, probf, probb);
        launch_gemm(probb, ETb, nullptr, ctx, NSLOT, H, S, S, S, H,
                    (long long)NSLOT * S, (long long)H * S, (long long)NSLOT * H, B, 0, nullptr);
        if (t == 0)
            gate_kernel<<<NB, 64, 0, stream>>>(ctx, Wg, bg, out + (size_t)NB * T * V);
        sw_kernel<<<NB, 256, 0, stream>>>(hf32, ctx, decinb, Wr, br, swv, t);
        launch_gemm(hnk, embb, nullptr, out + (size_t)t * V, NB, V, H, H, H,
                    (long long)T * V, 0, 0, 0, 1, 1, rowsumT + (size_t)t * NB);
        { dim3 g(NB, (V + 255) / 256); scale_kernel<<<g, 256, 0, stream>>>(out, swv, rowsumT + (size_t)t * NB, t); }
        scatter_kernel<<<NB, 256, 0, stream>>>(out, story, lens, swv, probf, t);
    }
}